// Round 18
// baseline (129.463 us; speedup 1.0000x reference)
//
#include <hip/hip_runtime.h>

// ---------------- problem constants ----------------
#define BATCH 2
#define SEQ   2048
#define NH    16
#define DH    64
#define DM    1024
#define MTOT  (BATCH*SEQ)  // 4096

typedef _Float16 f16x8 __attribute__((ext_vector_type(8)));
typedef _Float16 f16x4 __attribute__((ext_vector_type(4)));
typedef float    f32x4 __attribute__((ext_vector_type(4)));
typedef float    f32x16 __attribute__((ext_vector_type(16)));

#define LOG2E 1.44269504088896340736f

// workspace offsets (bytes) — total exactly 64 MB
#define OFF_X16  0u          //  8 MB
#define OFF_WQ   8388608u    //  2 MB
#define OFF_WK   10485760u
#define OFF_WV   12582912u
#define OFF_WO   14680064u
#define OFF_QA   16777216u   //  8 MB (stride 64 now)
#define OFF_KA   25165824u   //  8 MB (stride 64 now)
#define OFF_POS  33554432u   //  8 MB  pos[q][k] f16
#define OFF_PE16 41943040u   //  256 KB
#define OFF_VT   50331648u   //  8 MB
#define OFF_AO   58720256u   //  8 MB

__device__ __forceinline__ void gload_lds16(const _Float16* g, _Float16* l) {
  __builtin_amdgcn_global_load_lds(
      (const __attribute__((address_space(1))) unsigned int*)g,
      (__attribute__((address_space(3))) unsigned int*)l, 16, 0, 0);
}

__device__ __forceinline__ float fexp2(float x) {
  float r;
  asm("v_exp_f32 %0, %1" : "=v"(r) : "v"(x));
  return r;
}

__device__ __forceinline__ unsigned pk2(float a, float b) {
  auto v = __builtin_amdgcn_cvt_pkrtz(a, b);   // __fp16 ext_vector(2)
  return *(unsigned*)&v;
}

// ---------------- prep: fp32->fp16 cvt of x, weights, pe -------------------
__global__ __launch_bounds__(256) void prep(
    const float* __restrict__ x,  const float* __restrict__ wq,
    const float* __restrict__ wk, const float* __restrict__ wv,
    const float* __restrict__ wo, _Float16* __restrict__ dst,
    const float* __restrict__ pe, _Float16* __restrict__ pe16)
{
  int bid = blockIdx.x;
  const float* src;
  _Float16* d;
  if (bid < 4096) {
    int i = bid * 256 + threadIdx.x;   // each thread: 8 floats
    if (i < 524288) {
      src = x + (size_t)i * 8;
    } else {
      int j = i - 524288;
      int wi = j >> 17;                        // 131072 threads per weight
      const float* w = (wi == 0) ? wq : ((wi == 1) ? wk : ((wi == 2) ? wv : wo));
      src = w + (size_t)(j & 131071) * 8;
    }
    d = dst + (size_t)i * 8;
  } else {
    int i = (bid - 4096) * 256 + threadIdx.x;  // 16384 works: pe (2048*64 fp32)
    src = pe + (size_t)i * 8;
    d = pe16 + (size_t)i * 8;
  }
  float4 a = ((const float4*)src)[0];
  float4 c = ((const float4*)src)[1];
  f16x8 hv;
  hv[0]=(_Float16)a.x; hv[1]=(_Float16)a.y; hv[2]=(_Float16)a.z; hv[3]=(_Float16)a.w;
  hv[4]=(_Float16)c.x; hv[5]=(_Float16)c.y; hv[6]=(_Float16)c.z; hv[7]=(_Float16)c.w;
  *(f16x8*)d = hv;
}

// ---------------- pos_gemm: pos[q][k] = pe16[q] . pe16[k], K=64 ------------
// grid (16,16), 512 thr, 8 waves x (64x32); single K-tile.
__global__ __launch_bounds__(512) void pos_gemm(
    const _Float16* __restrict__ pe16, _Float16* __restrict__ pos)
{
  __shared__ _Float16 As[128 * 64];
  __shared__ _Float16 Bs[128 * 64];
  const int tid = threadIdx.x;
  const int w = tid >> 6, lane = tid & 63;
  const int g = lane >> 4, l16 = lane & 15;
  const int wm = w >> 2, wn = w & 3;
  const int mblk = blockIdx.y, nblk = blockIdx.x;

  #pragma unroll
  for (int ii = 0; ii < 2; ++ii) {       // A: 1024 16B-chunks / 512 thr
    int i = ii * 512 + tid;
    int rt = i >> 3, c = i & 7;
    int cg = c ^ (rt & 7);
    gload_lds16(pe16 + (size_t)(mblk * 128 + rt) * 64 + cg * 8, &As[i * 8]);
  }
  #pragma unroll
  for (int ii = 0; ii < 2; ++ii) {       // B
    int i = ii * 512 + tid;
    int rt = i >> 3, c = i & 7;
    int cg = c ^ (rt & 7);
    gload_lds16(pe16 + (size_t)(nblk * 128 + rt) * 64 + cg * 8, &Bs[i * 8]);
  }
  __syncthreads();

  f32x4 zero4 = {0.f, 0.f, 0.f, 0.f};
  f32x4 acc[4][2];
  #pragma unroll
  for (int mb = 0; mb < 4; ++mb)
    #pragma unroll
    for (int nb = 0; nb < 2; ++nb) acc[mb][nb] = zero4;
  #pragma unroll
  for (int ks = 0; ks < 2; ++ks) {
    f16x8 av[4], bv[2];
    #pragma unroll
    for (int mb = 0; mb < 4; ++mb) {
      int rt = wm * 64 + mb * 16 + l16;
      av[mb] = *(const f16x8*)&As[rt * 64 + (((ks * 4 + g) ^ (rt & 7)) * 8)];
    }
    #pragma unroll
    for (int nb = 0; nb < 2; ++nb) {
      int rt = wn * 32 + nb * 16 + l16;
      bv[nb] = *(const f16x8*)&Bs[rt * 64 + (((ks * 4 + g) ^ (rt & 7)) * 8)];
    }
    #pragma unroll
    for (int mb = 0; mb < 4; ++mb)
      #pragma unroll
      for (int nb = 0; nb < 2; ++nb)
        acc[mb][nb] = __builtin_amdgcn_mfma_f32_16x16x32_f16(
            av[mb], bv[nb], acc[mb][nb], 0, 0, 0);
  }
  #pragma unroll
  for (int nb = 0; nb < 2; ++nb) {
    int n = nblk * 128 + wn * 32 + nb * 16 + l16;
    #pragma unroll
    for (int mb = 0; mb < 4; ++mb) {
      int m0 = mblk * 128 + wm * 64 + mb * 16 + g * 4;
      #pragma unroll
      for (int r = 0; r < 4; ++r)
        pos[(size_t)(m0 + r) * SEQ + n] = (_Float16)acc[mb][nb][r];
    }
  }
}

// ---------------- NT GEMM: C(M x N) = A(M x K) * W(N x K)^T ----------------
// 8 waves (512 thr), 128x128 tile, XCD-aware block remap.
// MODE 0: 768 blocks (8x12 per XCD), epilogue -> Qa (scaled, stride 64),
//         Ka (stride 64), Vt transposed. MODE 1: 256 blocks (4x8), fp32 out.
template<int MODE>
__global__ __launch_bounds__(512) void gemm_nt(
    const _Float16* __restrict__ A,
    const _Float16* __restrict__ W0, const _Float16* __restrict__ W1,
    const _Float16* __restrict__ W2,
    const float* __restrict__ b0, const float* __restrict__ b1,
    const float* __restrict__ b2,
    _Float16* __restrict__ Qa, _Float16* __restrict__ Ka,
    _Float16* __restrict__ Vt, float* __restrict__ Out)
{
  __shared__ _Float16 As[128 * 64];
  __shared__ _Float16 Bs[128 * 64];
  const int tid = threadIdx.x;
  const int w = tid >> 6, lane = tid & 63;
  const int g = lane >> 4, l16 = lane & 15;
  const int wm = w >> 2, wn = w & 3;

  int lin = blockIdx.x;
  int xcd = lin & 7, j = lin >> 3;
  int mblk, nb_all;
  if (MODE == 0) { mblk = (xcd & 3) * 8 + (j & 7); nb_all = (xcd >> 2) * 12 + (j >> 3); }
  else           { mblk = xcd * 4 + (j & 3);       nb_all = j >> 2; }

  const _Float16* Bp; const float* biasp;
  int which = 0, nblk = nb_all;
  if (MODE == 0) {
    which = nb_all >> 3; nblk = nb_all & 7;
    Bp = (which == 0) ? W0 : ((which == 1) ? W1 : W2);
    biasp = (which == 0) ? b0 : ((which == 1) ? b1 : b2);
  } else {
    Bp = W0; biasp = b0;
  }

  f32x4 zero4 = {0.f, 0.f, 0.f, 0.f};
  f32x4 acc[4][2];
  #pragma unroll
  for (int mb = 0; mb < 4; ++mb)
    #pragma unroll
    for (int nb = 0; nb < 2; ++nb) acc[mb][nb] = zero4;

  const _Float16* Abase = A  + (size_t)mblk * 128 * DM;
  const _Float16* Bbase = Bp + (size_t)nblk * 128 * DM;

  for (int kt = 0; kt < DM / 64; ++kt) {
    __syncthreads();
    #pragma unroll
    for (int ii = 0; ii < 2; ++ii) {              // A
      int i = w * 2 + ii;
      int rt = i * 8 + (lane >> 3);
      int cg = (lane & 7) ^ (rt & 7);
      gload_lds16(Abase + (size_t)rt * DM + kt * 64 + cg * 8, &As[i * 512]);
    }
    #pragma unroll
    for (int ii = 0; ii < 2; ++ii) {              // B
      int i = w * 2 + ii;
      int rt = i * 8 + (lane >> 3);
      int cg = (lane & 7) ^ (rt & 7);
      gload_lds16(Bbase + (size_t)rt * DM + kt * 64 + cg * 8, &Bs[i * 512]);
    }
    __syncthreads();
    #pragma unroll
    for (int ks = 0; ks < 2; ++ks) {
      f16x8 av[4], bv[2];
      #pragma unroll
      for (int mb = 0; mb < 4; ++mb) {
        int rt = wm * 64 + mb * 16 + l16;
        av[mb] = *(const f16x8*)&As[rt * 64 + (((ks * 4 + g) ^ (rt & 7)) * 8)];
      }
      #pragma unroll
      for (int nb = 0; nb < 2; ++nb) {
        int rt = wn * 32 + nb * 16 + l16;
        bv[nb] = *(const f16x8*)&Bs[rt * 64 + (((ks * 4 + g) ^ (rt & 7)) * 8)];
      }
      #pragma unroll
      for (int mb = 0; mb < 4; ++mb)
        #pragma unroll
        for (int nb = 0; nb < 2; ++nb)
          acc[mb][nb] = __builtin_amdgcn_mfma_f32_16x16x32_f16(
              av[mb], bv[nb], acc[mb][nb], 0, 0, 0);
    }
  }

  // epilogue
  #pragma unroll
  for (int nb = 0; nb < 2; ++nb) {
    int n = nblk * 128 + wn * 32 + nb * 16 + l16;   // 0..1023 in selected W
    float bias = biasp[n];
    #pragma unroll
    for (int mb = 0; mb < 4; ++mb) {
      int m0 = mblk * 128 + wm * 64 + mb * 16 + g * 4;
      if (MODE == 0) {
        int hh = n >> 6, dd = n & 63;
        if (which == 2) {                    // V: write transposed Vt[bh,d,s]
          int bb = m0 >> 11, ss = m0 & 2047;
          f16x4 hv;
          #pragma unroll
          for (int r = 0; r < 4; ++r) hv[r] = (_Float16)(acc[mb][nb][r] + bias);
          *(f16x4*)&Vt[((size_t)((bb * NH + hh) * DH + dd)) * SEQ + ss] = hv;
        } else {                             // Q/K: stride 64 per-head
          #pragma unroll
          for (int r = 0; r < 4; ++r) {
            int m = m0 + r; int bb = m >> 11, ss = m & 2047;
            size_t o = ((size_t)((bb * NH + hh) * SEQ + ss)) * 64 + dd;
            if (which == 0) Qa[o] = (_Float16)((acc[mb][nb][r] + bias) * (0.125f * LOG2E));
            else            Ka[o] = (_Float16)(acc[mb][nb][r] + bias);
          }
        }
      } else {
        #pragma unroll
        for (int r = 0; r < 4; ++r)
          Out[(size_t)(m0 + r) * DM + n] = acc[mb][nb][r] + bias;
      }
    }
  }
}

// ---------------- flash attention (Da=64 + precomputed pos) ----------------
// 512 blocks (XCD-pinned); 4 waves x 32 q-rows. Swapped QK^T (32x32 MFMA,
// Dh=64 only), scores += alpha_h*LOG2E*pos[q][k] (pos tile staged in LDS),
// per-lane row softmax (q=lane&31), P in-register via permlane32_swap,
// O^T = Vt P^T. K/V/pos double-buffered, counted vmcnt(8).
// LDS: Ks 2x8K + Vs 2x8K + Pp 2x16K = 64KB -> 2 blocks/CU.
__global__ __launch_bounds__(256, 2) void flash_attn(
    const _Float16* __restrict__ Qa, const _Float16* __restrict__ Ka,
    const _Float16* __restrict__ Vt, const _Float16* __restrict__ Pos,
    const float* __restrict__ alpha, const int* __restrict__ mask,
    _Float16* __restrict__ AO)
{
  __shared__ _Float16 Ks[2][64 * 64];   // [key][d]   swizzled (8 x 16B chunks)
  __shared__ _Float16 Vs[2][64 * 64];   // [d][key]   swizzled
  __shared__ _Float16 Pp[2][128 * 64];  // [q][key]   swizzled (pos tile)
  const int tid = threadIdx.x;
  const int w = tid >> 6, lane = tid & 63;
  const int l32 = lane & 31, hi = lane >> 5;

  int bid = blockIdx.x;                  // 512 blocks: bid&7 -> XCD
  int work = (bid & 7) * 64 + (bid >> 3);
  const int qt = work & 15;              // 16 q-tiles of 128
  const int bh = work >> 4;              // 4 bh per XCD
  const int h = bh & 15, b = bh >> 4;

  // Q (content only, pre-scaled 0.125*LOG2E): col=q=l32, k-chunk hi
  const _Float16* qbase = Qa + ((size_t)(bh * SEQ) + qt * 128 + w * 32) * 64;
  f16x8 qf[4];
  #pragma unroll
  for (int c16 = 0; c16 < 4; ++c16)
    qf[c16] = *(const f16x8*)&qbase[l32 * 64 + c16 * 16 + hi * 8];

  const float alf = alpha[h] * LOG2E;

  f32x16 acco[2];                        // O^T: d=db*32+(r&3)+8*(r>>2)+4*hi, q=l32
  #pragma unroll
  for (int db = 0; db < 2; ++db)
    #pragma unroll
    for (int r = 0; r < 16; ++r) acco[db][r] = 0.f;
  float mrun = -3.0e38f, lrun = 0.f;

  const _Float16* kbase = Ka + (size_t)bh * SEQ * 64;
  const _Float16* vbase = Vt + (size_t)bh * DH * SEQ;
  const _Float16* pbase = Pos + (size_t)(qt * 128) * SEQ;
  const int* mbase = mask + b * SEQ;

  // wave-uniform mask precheck (all-ones in practice)
  int allm = 1;
  #pragma unroll 8
  for (int t = 0; t < SEQ / 64; ++t) allm &= (mbase[t * 64 + lane] != 0);
  const bool maskclean = __all(allm);

  auto STAGE = [&](int buf, int kt) {     // 8 gloads/thread
    #pragma unroll
    for (int ii = 0; ii < 2; ++ii) {      // K: 512 16B-chunks / 256 thr
      int i = ii * 256 + tid;
      int rt = i >> 3, c = i & 7;
      int cg = c ^ (rt & 7);
      gload_lds16(kbase + (size_t)(kt * 64 + rt) * 64 + cg * 8, &Ks[buf][i * 8]);
    }
    #pragma unroll
    for (int ii = 0; ii < 2; ++ii) {      // V: 512 chunks
      int i = ii * 256 + tid;
      int rt = i >> 3, c = i & 7;
      int cg = c ^ (rt & 7);
      gload_lds16(vbase + (size_t)rt * SEQ + kt * 64 + cg * 8, &Vs[buf][i * 8]);
    }
    #pragma unroll
    for (int ii = 0; ii < 4; ++ii) {      // pos: 1024 chunks (128 q x 64 k)
      int i = ii * 256 + tid;
      int rt = i >> 3, c = i & 7;
      int cg = c ^ (rt & 7);
      gload_lds16(pbase + (size_t)rt * SEQ + kt * 64 + cg * 8, &Pp[buf][i * 8]);
    }
  };

  STAGE(0, 0);
  int cur = 0;
  for (int kt = 0; kt < SEQ / 64; ++kt) {
    asm volatile("s_waitcnt lgkmcnt(0)" ::: "memory");
    __builtin_amdgcn_s_barrier();
    asm volatile("" ::: "memory");
    if (kt + 1 < SEQ / 64) {
      STAGE(cur ^ 1, kt + 1);                 // prefetch next tile
      asm volatile("s_waitcnt vmcnt(8)" ::: "memory");  // tile kt landed
    } else {
      asm volatile("s_waitcnt vmcnt(0)" ::: "memory");
    }
    __builtin_amdgcn_s_barrier();
    asm volatile("" ::: "memory");

    // QK^T (content): S^T[key][q], 2 key-blocks of 32
    f32x16 sfr[2];
    __builtin_amdgcn_s_setprio(1);
    #pragma unroll
    for (int kb = 0; kb < 2; ++kb) {
      f32x16 s;
      #pragma unroll
      for (int r = 0; r < 16; ++r) s[r] = 0.f;
      int rt = kb * 32 + l32;
      #pragma unroll
      for (int c16 = 0; c16 < 4; ++c16) {
        int ch = (c16 * 2 + hi) ^ (rt & 7);
        f16x8 kf = *(const f16x8*)&Ks[cur][rt * 64 + ch * 8];
        s = __builtin_amdgcn_mfma_f32_32x32x16_f16(kf, qf[c16], s, 0, 0, 0);
      }
      sfr[kb] = s;
    }
    __builtin_amdgcn_s_setprio(0);

    // add positional scores: sfr[kb][rq*4+j] += alf * pos[q][key]
    {
      int row = w * 32 + l32;             // q within block's 128
      int sw8 = (row & 7);
      #pragma unroll
      for (int kb = 0; kb < 2; ++kb)
        #pragma unroll
        for (int rq = 0; rq < 4; ++rq) {
          int G = kb * 8 + rq * 2 + hi;   // 8B granule (4 f16 keys)
          f16x4 p4 = *(const f16x4*)&Pp[cur][row * 64 + (((G >> 1) ^ sw8) * 8) + (G & 1) * 4];
          sfr[kb][rq * 4 + 0] += alf * (float)p4[0];
          sfr[kb][rq * 4 + 1] += alf * (float)p4[1];
          sfr[kb][rq * 4 + 2] += alf * (float)p4[2];
          sfr[kb][rq * 4 + 3] += alf * (float)p4[3];
        }
    }

    // rare slow path: mask pre-max (never taken for all-ones mask)
    if (!maskclean) {
      #pragma unroll
      for (int kb = 0; kb < 2; ++kb)
        #pragma unroll
        for (int r = 0; r < 16; ++r) {
          int key = kt * 64 + kb * 32 + (r & 3) + 8 * (r >> 2) + 4 * hi;
          if (mbase[key] == 0) sfr[kb][r] = -3.0e38f;
        }
    }

    // per-lane row softmax for q=l32 (lane pair (l32, l32+32) splits keys)
    float mx = sfr[0][0];
    #pragma unroll
    for (int kb = 0; kb < 2; ++kb)
      #pragma unroll
      for (int r = 0; r < 16; ++r) mx = fmaxf(mx, sfr[kb][r]);
    mx = fmaxf(mx, __shfl_xor(mx, 32));

    const bool rescale = !__all(mx <= mrun + 8.0f);   // defer-max THR=8
    float mnew = mrun, scale = 1.0f;
    if (rescale) {
      mnew = fmaxf(mrun, mx);
      scale = fexp2(mrun - mnew);
    }
    float rsum = 0.f;
    unsigned pk[2][4][2];                 // [kb][quad rq][u32 pair]
    #pragma unroll
    for (int kb = 0; kb < 2; ++kb)
      #pragma unroll
      for (int rq = 0; rq < 4; ++rq) {
        float p0 = fexp2(sfr[kb][rq * 4 + 0] - mnew);
        float p1 = fexp2(sfr[kb][rq * 4 + 1] - mnew);
        float p2 = fexp2(sfr[kb][rq * 4 + 2] - mnew);
        float p3 = fexp2(sfr[kb][rq * 4 + 3] - mnew);
        rsum += (p0 + p1) + (p2 + p3);
        pk[kb][rq][0] = pk2(p0, p1);
        pk[kb][rq][1] = pk2(p2, p3);
      }
    rsum += __shfl_xor(rsum, 32);
    if (rescale) {
      lrun = lrun * scale + rsum;
      mrun = mnew;
      #pragma unroll
      for (int db = 0; db < 2; ++db)
        #pragma unroll
        for (int r = 0; r < 16; ++r) acco[db][r] *= scale;
    } else {
      lrun += rsum;
    }

    // PV: O^T += Vt * P^T; pf built per 16-key chunk via permlane32_swap
    __builtin_amdgcn_s_setprio(1);
    #pragma unroll
    for (int c = 0; c < 4; ++c) {         // k-chunk of 16 keys
      const int kb = c >> 1, c2 = c & 1;
      unsigned X0 = pk[kb][2 * c2][0],     X1 = pk[kb][2 * c2][1];
      unsigned Y0 = pk[kb][2 * c2 + 1][0], Y1 = pk[kb][2 * c2 + 1][1];
      asm("v_permlane32_swap_b32 %0, %1" : "+v"(X0), "+v"(Y0));
      asm("v_permlane32_swap_b32 %0, %1" : "+v"(X1), "+v"(Y1));
      union { unsigned u[4]; f16x8 v; } pu;
      pu.u[0] = X0; pu.u[1] = X1; pu.u[2] = Y0; pu.u[3] = Y1;
      #pragma unroll
      for (int db = 0; db < 2; ++db) {
        int row = db * 32 + l32;
        int ch = (2 * c + hi) ^ (row & 7);
        f16x8 vf = *(const f16x8*)&Vs[cur][row * 64 + ch * 8];
        acco[db] = __builtin_amdgcn_mfma_f32_32x32x16_f16(vf, pu.v, acco[db], 0, 0, 0);
      }
    }
    __builtin_amdgcn_s_setprio(0);
    cur ^= 1;
  }

  // epilogue: AO[b, sg, h*64+d] = O^T[d][q]/l
  float inv = 1.0f / lrun;
  int sg = qt * 128 + w * 32 + l32;
  _Float16* aobase = AO + ((size_t)(b * SEQ + sg)) * DM + h * DH;
  #pragma unroll
  for (int db = 0; db < 2; ++db)
    #pragma unroll
    for (int rq = 0; rq < 4; ++rq) {
      f16x4 o;
      #pragma unroll
      for (int j = 0; j < 4; ++j) o[j] = (_Float16)(acco[db][rq * 4 + j] * inv);
      *(f16x4*)&aobase[db * 32 + rq * 8 + hi * 4] = o;
    }
}

// ---------------- launch ----------------
extern "C" void kernel_launch(void* const* d_in, const int* in_sizes, int n_in,
                              void* d_out, int out_size, void* d_ws, size_t ws_size,
                              hipStream_t stream) {
  const float* x     = (const float*)d_in[0];
  const int*   mask  = (const int*)  d_in[1];
  const float* Wq    = (const float*)d_in[2];
  const float* bq    = (const float*)d_in[3];
  const float* Wk    = (const float*)d_in[4];
  const float* bk    = (const float*)d_in[5];
  const float* Wv    = (const float*)d_in[6];
  const float* bv    = (const float*)d_in[7];
  const float* Wo    = (const float*)d_in[8];
  const float* bo    = (const float*)d_in[9];
  const float* pe    = (const float*)d_in[10];
  const float* alpha = (const float*)d_in[11];
  // beta (d_in[12]) is softmax-invariant (uniform per row) -> unused

  char* ws = (char*)d_ws;
  _Float16* x16  = (_Float16*)(ws + OFF_X16);
  _Float16* wq6  = (_Float16*)(ws + OFF_WQ);
  _Float16* wk6  = (_Float16*)(ws + OFF_WK);
  _Float16* wv6  = (_Float16*)(ws + OFF_WV);
  _Float16* wo6  = (_Float16*)(ws + OFF_WO);
  _Float16* Qa   = (_Float16*)(ws + OFF_QA);
  _Float16* Ka   = (_Float16*)(ws + OFF_KA);
  _Float16* Pos  = (_Float16*)(ws + OFF_POS);
  _Float16* pe16 = (_Float16*)(ws + OFF_PE16);
  _Float16* Vt   = (_Float16*)(ws + OFF_VT);
  _Float16* AO   = (_Float16*)(ws + OFF_AO);
  float* out = (float*)d_out;

  prep<<<4160, 256, 0, stream>>>(x, Wq, Wk, Wv, Wo, x16, pe, pe16);
  pos_gemm<<<dim3(16, 16), 512, 0, stream>>>(pe16, Pos);
  gemm_nt<0><<<768, 512, 0, stream>>>(x16, wq6, wk6, wv6, bq, bk, bv,
                                      Qa, Ka, Vt, nullptr);
  flash_attn<<<512, 256, 0, stream>>>(Qa, Ka, Vt, Pos, alpha, mask, AO);
  gemm_nt<1><<<256, 512, 0, stream>>>(AO, wo6, nullptr, nullptr, bo,
                                      nullptr, nullptr, nullptr, nullptr,
                                      nullptr, out);
}

// Round 19
// 127.952 us; speedup vs baseline: 1.0118x; 1.0118x over previous
//
#include <hip/hip_runtime.h>

// ---------------- problem constants ----------------
#define BATCH 2
#define SEQ   2048
#define NH    16
#define DH    64
#define DA    128          // augmented head dim (content 64 + pos 64)
#define DM    1024
#define MTOT  (BATCH*SEQ)  // 4096

typedef _Float16 f16x8 __attribute__((ext_vector_type(8)));
typedef _Float16 f16x4 __attribute__((ext_vector_type(4)));
typedef float    f32x4 __attribute__((ext_vector_type(4)));
typedef float    f32x16 __attribute__((ext_vector_type(16)));

#define LOG2E 1.44269504088896340736f

// workspace offsets (bytes)
#define OFF_X16 0u
#define OFF_WQ  8388608u
#define OFF_WK  10485760u
#define OFF_WV  12582912u
#define OFF_WO  14680064u
#define OFF_QA  16777216u
#define OFF_KA  33554432u
#define OFF_VT  50331648u
#define OFF_AO  58720256u
// total 67108864 (64 MB)

__device__ __forceinline__ void gload_lds16(const _Float16* g, _Float16* l) {
  __builtin_amdgcn_global_load_lds(
      (const __attribute__((address_space(1))) unsigned int*)g,
      (__attribute__((address_space(3))) unsigned int*)l, 16, 0, 0);
}

__device__ __forceinline__ float fexp2(float x) {
  float r;
  asm("v_exp_f32 %0, %1" : "=v"(r) : "v"(x));
  return r;
}

__device__ __forceinline__ unsigned pk2(float a, float b) {
  auto v = __builtin_amdgcn_cvt_pkrtz(a, b);   // __fp16 ext_vector(2)
  return *(unsigned*)&v;
}

// ---------------- prep: fp32->fp16 cvt (x + weights) AND pe fill, fused ----
__global__ __launch_bounds__(256) void prep(
    const float* __restrict__ x,  const float* __restrict__ wq,
    const float* __restrict__ wk, const float* __restrict__ wv,
    const float* __restrict__ wo, _Float16* __restrict__ dst,
    const float* __restrict__ pe, const float* __restrict__ alpha,
    _Float16* __restrict__ Qa, _Float16* __restrict__ Ka)
{
  int bid = blockIdx.x;
  if (bid < 4096) {
    int i = bid * 256 + threadIdx.x;   // each thread: 8 floats
    const float* src;
    if (i < 524288) {
      src = x + (size_t)i * 8;
    } else {
      int j = i - 524288;
      int wi = j >> 17;                        // 131072 threads per weight
      const float* w = (wi == 0) ? wq : ((wi == 1) ? wk : ((wi == 2) ? wv : wo));
      src = w + (size_t)(j & 131071) * 8;
    }
    float4 a = ((const float4*)src)[0];
    float4 c = ((const float4*)src)[1];
    f16x8 hv;
    hv[0]=(_Float16)a.x; hv[1]=(_Float16)a.y; hv[2]=(_Float16)a.z; hv[3]=(_Float16)a.w;
    hv[4]=(_Float16)c.x; hv[5]=(_Float16)c.y; hv[6]=(_Float16)c.z; hv[7]=(_Float16)c.w;
    *(f16x8*)(dst + (size_t)i * 8) = hv;
  } else {
    int idx = (bid - 4096) * 256 + threadIdx.x;   // B*H*S*8 = 2^19 works
    int c8 = idx & 7;
    int s  = (idx >> 3) & 2047;
    int h  = (idx >> 14) & 15;
    int b  = idx >> 18;
    const float4* p4 = (const float4*)(pe + s * 64 + c8 * 8);
    float4 a = p4[0], c = p4[1];
    float al = alpha[h] * LOG2E;
    f16x8 hk, hq;
    hk[0]=(_Float16)a.x; hk[1]=(_Float16)a.y; hk[2]=(_Float16)a.z; hk[3]=(_Float16)a.w;
    hk[4]=(_Float16)c.x; hk[5]=(_Float16)c.y; hk[6]=(_Float16)c.z; hk[7]=(_Float16)c.w;
    hq[0]=(_Float16)(al*a.x); hq[1]=(_Float16)(al*a.y); hq[2]=(_Float16)(al*a.z); hq[3]=(_Float16)(al*a.w);
    hq[4]=(_Float16)(al*c.x); hq[5]=(_Float16)(al*c.y); hq[6]=(_Float16)(al*c.z); hq[7]=(_Float16)(al*c.w);
    size_t o = ((size_t)((b * NH + h) * SEQ + s)) * DA + 64 + c8 * 8;
    *(f16x8*)&Qa[o] = hq;
    *(f16x8*)&Ka[o] = hk;
  }
}

// ---------------- NT GEMM: C(M x N) = A(M x K) * W(N x K)^T ----------------
// 8 waves (512 thr), 128x128 tile, per-wave 64x32. 1D grid with XCD-aware
// block->(mblk,nb) remap (lin%8 = XCD): each XCD owns a contiguous
// mblk-band x nb-band -> A/B panels L2-resident per XCD.
// MODE 0: 768 blocks, XCD tile = 8 mblk x 12 nb. MODE 1: 256 blocks, 4 x 8.
template<int MODE>
__global__ __launch_bounds__(512) void gemm_nt(
    const _Float16* __restrict__ A,
    const _Float16* __restrict__ W0, const _Float16* __restrict__ W1,
    const _Float16* __restrict__ W2,
    const float* __restrict__ b0, const float* __restrict__ b1,
    const float* __restrict__ b2,
    _Float16* __restrict__ Qa, _Float16* __restrict__ Ka,
    _Float16* __restrict__ Vt, float* __restrict__ Out)
{
  __shared__ _Float16 As[128 * 64];
  __shared__ _Float16 Bs[128 * 64];
  const int tid = threadIdx.x;
  const int w = tid >> 6, lane = tid & 63;
  const int g = lane >> 4, l16 = lane & 15;
  const int wm = w >> 2, wn = w & 3;

  int lin = blockIdx.x;
  int xcd = lin & 7, j = lin >> 3;
  int mblk, nb_all;
  if (MODE == 0) { mblk = (xcd & 3) * 8 + (j & 7); nb_all = (xcd >> 2) * 12 + (j >> 3); }
  else           { mblk = xcd * 4 + (j & 3);       nb_all = j >> 2; }

  const _Float16* Bp; const float* biasp;
  int which = 0, nblk = nb_all;
  if (MODE == 0) {
    which = nb_all >> 3; nblk = nb_all & 7;
    Bp = (which == 0) ? W0 : ((which == 1) ? W1 : W2);
    biasp = (which == 0) ? b0 : ((which == 1) ? b1 : b2);
  } else {
    Bp = W0; biasp = b0;
  }

  f32x4 zero4 = {0.f, 0.f, 0.f, 0.f};
  f32x4 acc[4][2];
  #pragma unroll
  for (int mb = 0; mb < 4; ++mb)
    #pragma unroll
    for (int nb = 0; nb < 2; ++nb) acc[mb][nb] = zero4;

  const _Float16* Abase = A  + (size_t)mblk * 128 * DM;
  const _Float16* Bbase = Bp + (size_t)nblk * 128 * DM;

  for (int kt = 0; kt < DM / 64; ++kt) {
    __syncthreads();
    #pragma unroll
    for (int ii = 0; ii < 2; ++ii) {              // A: 16 chunk-groups / 8 waves
      int i = w * 2 + ii;
      int rt = i * 8 + (lane >> 3);
      int cg = (lane & 7) ^ (rt & 7);
      gload_lds16(Abase + (size_t)rt * DM + kt * 64 + cg * 8, &As[i * 512]);
    }
    #pragma unroll
    for (int ii = 0; ii < 2; ++ii) {              // B
      int i = w * 2 + ii;
      int rt = i * 8 + (lane >> 3);
      int cg = (lane & 7) ^ (rt & 7);
      gload_lds16(Bbase + (size_t)rt * DM + kt * 64 + cg * 8, &Bs[i * 512]);
    }
    __syncthreads();
    #pragma unroll
    for (int ks = 0; ks < 2; ++ks) {
      f16x8 av[4], bv[2];
      #pragma unroll
      for (int mb = 0; mb < 4; ++mb) {
        int rt = wm * 64 + mb * 16 + l16;
        av[mb] = *(const f16x8*)&As[rt * 64 + (((ks * 4 + g) ^ (rt & 7)) * 8)];
      }
      #pragma unroll
      for (int nb = 0; nb < 2; ++nb) {
        int rt = wn * 32 + nb * 16 + l16;
        bv[nb] = *(const f16x8*)&Bs[rt * 64 + (((ks * 4 + g) ^ (rt & 7)) * 8)];
      }
      #pragma unroll
      for (int mb = 0; mb < 4; ++mb)
        #pragma unroll
        for (int nb = 0; nb < 2; ++nb)
          acc[mb][nb] = __builtin_amdgcn_mfma_f32_16x16x32_f16(
              av[mb], bv[nb], acc[mb][nb], 0, 0, 0);
    }
  }

  // epilogue
  #pragma unroll
  for (int nb = 0; nb < 2; ++nb) {
    int n = nblk * 128 + wn * 32 + nb * 16 + l16;   // 0..1023 in selected W
    float bias = biasp[n];
    #pragma unroll
    for (int mb = 0; mb < 4; ++mb) {
      int m0 = mblk * 128 + wm * 64 + mb * 16 + g * 4;
      if (MODE == 0) {
        int hh = n >> 6, dd = n & 63;
        if (which == 2) {                    // V: write transposed Vt[bh,d,s]
          int bb = m0 >> 11, ss = m0 & 2047;
          f16x4 hv;
          #pragma unroll
          for (int r = 0; r < 4; ++r) hv[r] = (_Float16)(acc[mb][nb][r] + bias);
          *(f16x4*)&Vt[((size_t)((bb * NH + hh) * DH + dd)) * SEQ + ss] = hv;
        } else {
          #pragma unroll
          for (int r = 0; r < 4; ++r) {
            int m = m0 + r; int bb = m >> 11, ss = m & 2047;
            size_t o = ((size_t)((bb * NH + hh) * SEQ + ss)) * DA + dd;
            if (which == 0) Qa[o] = (_Float16)((acc[mb][nb][r] + bias) * (0.125f * LOG2E));
            else            Ka[o] = (_Float16)(acc[mb][nb][r] + bias);
          }
        }
      } else {
        #pragma unroll
        for (int r = 0; r < 4; ++r)
          Out[(size_t)(m0 + r) * DM + n] = acc[mb][nb][r] + bias;
      }
    }
  }
}

// ---------------- flash attention (round-14 version: best measured) --------
// 512 blocks (XCD-pinned); 4 waves x 32 q-rows. Swapped QK^T (S^T = K Q^T),
// O^T = Vt P^T -> q = lane&31 everywhere, rescale lane-uniform.
// P relayout S^T->P^T-fragment via v_permlane32_swap (no P LDS).
// LDS 48KB. Counted vmcnt(6) dbuf staging.
__global__ __launch_bounds__(256, 3) void flash_attn(
    const _Float16* __restrict__ Qa, const _Float16* __restrict__ Ka,
    const _Float16* __restrict__ Vt, const int* __restrict__ mask,
    _Float16* __restrict__ AO)
{
  __shared__ _Float16 Ks[2][64 * 128];  // 2 x 16KB  [key][Da] swizzled
  __shared__ _Float16 Vs[2][64 * 64];   // 2 x 8KB   [d][key] swizzled
  const int tid = threadIdx.x;
  const int w = tid >> 6, lane = tid & 63;
  const int l32 = lane & 31, hi = lane >> 5;

  int bid = blockIdx.x;                  // 512 blocks: bid&7 -> XCD
  int work = (bid & 7) * 64 + (bid >> 3);
  const int qt = work & 15;              // 16 q-tiles of 128
  const int bh = work >> 4;              // 4 bh per XCD -> K/V L2-resident
  const int h = bh & 15, b = bh >> 4;

  // Q as B-operand: col=q=l32, k-chunk hi -> Q[q][c16*16 + hi*8 + j]
  const _Float16* qbase = Qa + ((size_t)(bh * SEQ) + qt * 128 + w * 32) * DA;
  f16x8 qf[8];
  #pragma unroll
  for (int c16 = 0; c16 < 8; ++c16)
    qf[c16] = *(const f16x8*)&qbase[l32 * DA + c16 * 16 + hi * 8];

  f32x16 acco[2];                        // O^T: d=(reg&3)+8*(reg>>2)+4*hi+32*db, q=l32
  #pragma unroll
  for (int db = 0; db < 2; ++db)
    #pragma unroll
    for (int r = 0; r < 16; ++r) acco[db][r] = 0.f;
  float mrun = -3.0e38f, lrun = 0.f;

  const _Float16* kbase = Ka + (size_t)bh * SEQ * DA;
  const _Float16* vbase = Vt + (size_t)bh * DH * SEQ;
  const int* mbase = mask + b * SEQ;

  // wave-uniform mask precheck (all-ones in practice)
  int allm = 1;
  #pragma unroll 8
  for (int t = 0; t < SEQ / 64; ++t) allm &= (mbase[t * 64 + lane] != 0);
  const bool maskclean = __all(allm);

  auto STAGE = [&](int buf, int kt) {
    #pragma unroll
    for (int ii = 0; ii < 4; ++ii) {          // K: 1024 16B-chunks / 256 thr
      int i = ii * 256 + tid;
      int rt = i >> 4, c = i & 15;
      int cg = c ^ (rt & 7);
      gload_lds16(kbase + (size_t)(kt * 64 + rt) * DA + cg * 8, &Ks[buf][i * 8]);
    }
    #pragma unroll
    for (int ii = 0; ii < 2; ++ii) {          // V: 512 chunks / 256 thr
      int i = ii * 256 + tid;
      int rt = i >> 3, c = i & 7;
      int cg = c ^ (rt & 7);
      gload_lds16(vbase + (size_t)rt * SEQ + kt * 64 + cg * 8, &Vs[buf][i * 8]);
    }
  };

  STAGE(0, 0);
  int cur = 0;
  for (int kt = 0; kt < SEQ / 64; ++kt) {
    asm volatile("s_waitcnt lgkmcnt(0)" ::: "memory");
    __builtin_amdgcn_s_barrier();
    asm volatile("" ::: "memory");
    if (kt + 1 < SEQ / 64) {
      STAGE(cur ^ 1, kt + 1);                 // prefetch next tile
      asm volatile("s_waitcnt vmcnt(6)" ::: "memory");  // tile kt landed
    } else {
      asm volatile("s_waitcnt vmcnt(0)" ::: "memory");
    }
    __builtin_amdgcn_s_barrier();
    asm volatile("" ::: "memory");

    // QK^T: S^T[key][q], 2 key-blocks of 32
    f32x16 sfr[2];
    __builtin_amdgcn_s_setprio(1);
    #pragma unroll
    for (int kb = 0; kb < 2; ++kb) {
      f32x16 s;
      #pragma unroll
      for (int r = 0; r < 16; ++r) s[r] = 0.f;
      int rt = kb * 32 + l32;
      #pragma unroll
      for (int c16 = 0; c16 < 8; ++c16) {
        int ch = (2 * c16 + hi) ^ (rt & 7);
        f16x8 kf = *(const f16x8*)&Ks[cur][rt * 128 + ch * 8];
        s = __builtin_amdgcn_mfma_f32_32x32x16_f16(kf, qf[c16], s, 0, 0, 0);
      }
      sfr[kb] = s;
    }
    __builtin_amdgcn_s_setprio(0);

    // rare slow path: mask pre-max (never taken for all-ones mask)
    if (!maskclean) {
      #pragma unroll
      for (int kb = 0; kb < 2; ++kb)
        #pragma unroll
        for (int r = 0; r < 16; ++r) {
          int key = kt * 64 + kb * 32 + (r & 3) + 8 * (r >> 2) + 4 * hi;
          if (mbase[key] == 0) sfr[kb][r] = -3.0e38f;
        }
    }

    // per-lane row softmax for q=l32 (lane pair (l32, l32+32) splits keys)
    float mx = sfr[0][0];
    #pragma unroll
    for (int kb = 0; kb < 2; ++kb)
      #pragma unroll
      for (int r = 0; r < 16; ++r) mx = fmaxf(mx, sfr[kb][r]);
    mx = fmaxf(mx, __shfl_xor(mx, 32));

    const bool rescale = !__all(mx <= mrun + 8.0f);   // defer-max THR=8
    float mnew = mrun, scale = 1.0f;
    if (rescale) {
      mnew = fmaxf(mrun, mx);
      scale = fexp2(mrun - mnew);
    }
    float rsum = 0.f;
    unsigned pk[2][4][2];                 // [kb][quad rq][u32 pair]
    #pragma unroll
    for (int kb = 0; kb < 2; ++kb)
      #pragma unroll
      for (int rq = 0; rq < 4; ++rq) {
        float p0 = fexp2(sfr[kb][rq * 4 + 0] - mnew);
        float p1 = fexp2(sfr[kb][rq * 4 + 1] - mnew);
        float p2 = fexp2(sfr[kb][rq * 4 + 2] - mnew);
        float p3 = fexp2(sfr[kb][rq * 4 + 3] - mnew);
        rsum += (p0 + p1) + (p2 + p3);
        pk[kb][rq][0] = pk2(p0, p1);
        pk[kb][rq][1] = pk2(p2, p3);
      }
    rsum += __shfl_xor(rsum, 32);
    if (rescale) {
      lrun = lrun * scale + rsum;
      mrun = mnew;
      #pragma unroll
      for (int db = 0; db < 2; ++db)
        #pragma unroll
        for (int r = 0; r < 16; ++r) acco[db][r] *= scale;
    } else {
      lrun += rsum;
    }

    // PV: O^T += Vt * P^T; pf built per 16-key chunk via permlane32_swap
    __builtin_amdgcn_s_setprio(1);
    #pragma unroll
    for (int c = 0; c < 4; ++c) {         // k-chunk of 16 keys
      const int kb = c >> 1, c2 = c & 1;
      unsigned X0 = pk[kb][2 * c2][0],     X1 = pk[kb][2 * c2][1];
      unsigned Y0 = pk[kb][2 * c2 + 1][0], Y1 = pk[kb][2 * c2 + 1][1];
      asm("v_permlane32_swap_b32 %0, %1" : "+v"(X0), "+v"(Y0));
      asm("v_permlane32_swap_b32 %0, %1" : "+v"(X1), "+v"(Y1));
      union { unsigned u[4]; f16x8 v; } pu;
      pu.u[0] = X0; pu.u[1] = X1; pu.u[2] = Y0; pu.u[3] = Y1;
      #pragma unroll
      for (int db = 0; db < 2; ++db) {
        int row = db * 32 + l32;
        int ch = (2 * c + hi) ^ (row & 7);
        f16x8 vf = *(const f16x8*)&Vs[cur][row * 64 + ch * 8];
        acco[db] = __builtin_amdgcn_mfma_f32_32x32x16_f16(vf, pu.v, acco[db], 0, 0, 0);
      }
    }
    __builtin_amdgcn_s_setprio(0);
    cur ^= 1;
  }

  // epilogue: AO[b, sg, h*64+d] = O^T[d][q]/l ; d = db*32 + rq*8 + hi*4 + j
  float inv = 1.0f / lrun;
  int sg = qt * 128 + w * 32 + l32;
  _Float16* aobase = AO + ((size_t)(b * SEQ + sg)) * DM + h * DH;
  #pragma unroll
  for (int db = 0; db < 2; ++db)
    #pragma unroll
    for (int rq = 0; rq < 4; ++rq) {
      f16x4 o;
      #pragma unroll
      for (int j = 0; j < 4; ++j) o[j] = (_Float16)(acco[db][rq * 4 + j] * inv);
      *(f16x4*)&aobase[db * 32 + rq * 8 + hi * 4] = o;
    }
}

// ---------------- launch ----------------
extern "C" void kernel_launch(void* const* d_in, const int* in_sizes, int n_in,
                              void* d_out, int out_size, void* d_ws, size_t ws_size,
                              hipStream_t stream) {
  const float* x     = (const float*)d_in[0];
  const int*   mask  = (const int*)  d_in[1];
  const float* Wq    = (const float*)d_in[2];
  const float* bq    = (const float*)d_in[3];
  const float* Wk    = (const float*)d_in[4];
  const float* bk    = (const float*)d_in[5];
  const float* Wv    = (const float*)d_in[6];
  const float* bv    = (const float*)d_in[7];
  const float* Wo    = (const float*)d_in[8];
  const float* bo    = (const float*)d_in[9];
  const float* pe    = (const float*)d_in[10];
  const float* alpha = (const float*)d_in[11];
  // beta (d_in[12]) is softmax-invariant (uniform per row) -> unused

  char* ws = (char*)d_ws;
  _Float16* x16 = (_Float16*)(ws + OFF_X16);
  _Float16* wq6 = (_Float16*)(ws + OFF_WQ);
  _Float16* wk6 = (_Float16*)(ws + OFF_WK);
  _Float16* wv6 = (_Float16*)(ws + OFF_WV);
  _Float16* wo6 = (_Float16*)(ws + OFF_WO);
  _Float16* Qa  = (_Float16*)(ws + OFF_QA);
  _Float16* Ka  = (_Float16*)(ws + OFF_KA);
  _Float16* Vt  = (_Float16*)(ws + OFF_VT);
  _Float16* AO  = (_Float16*)(ws + OFF_AO);
  float* out = (float*)d_out;

  prep<<<6144, 256, 0, stream>>>(x, Wq, Wk, Wv, Wo, x16, pe, alpha, Qa, Ka);
  gemm_nt<0><<<768, 512, 0, stream>>>(x16, wq6, wk6, wv6, bq, bk, bv,
                                      Qa, Ka, Vt, nullptr);
  flash_attn<<<512, 256, 0, stream>>>(Qa, Ka, Vt, mask, AO);
  gemm_nt<1><<<256, 512, 0, stream>>>(AO, wo6, nullptr, nullptr, bo,
                                      nullptr, nullptr, nullptr, nullptr,
                                      nullptr, out);
}